// Round 3
// baseline (463.978 us; speedup 1.0000x reference)
//
#include <hip/hip_runtime.h>
#include <hip/hip_bf16.h>
#include <math.h>

#define B_ 2
#define NA_ 4096
#define NR_ 512
#define D_ 128
#define H_ 8
#define DH_ 16
#define NLOCAL_ 5
#define NIPA_ 4
#define NITER_ 3

__device__ __forceinline__ float gelu_tanh(float x) {
  float x3 = x * x * x;
  return 0.5f * x * (1.0f + tanhf(0.7978845608028654f * (x + 0.044715f * x3)));
}

// pack two floats as bf16 (RNE) into one uint: lo in low half, hi in high half
__device__ __forceinline__ unsigned int pack_bf(float lo, float hi) {
  unsigned int a = __float_as_uint(lo);
  unsigned int b = __float_as_uint(hi);
  a = (a + 0x7fffu + ((a >> 16) & 1u)) >> 16;
  b = (b + 0x7fffu + ((b >> 16) & 1u)) & 0xffff0000u;
  return b | a;
}
__device__ __forceinline__ float bf_lo(unsigned int u) { return __uint_as_float(u << 16); }
__device__ __forceinline__ float bf_hi(unsigned int u) { return __uint_as_float(u & 0xffff0000u); }

// ---------------- weight pre-pack: fp32 -> bf16 colpair uints ----------------
// lwb:   [5][128][64]    localW
// qkvb:  [4][3][128][64] Wq/Wk/Wv
// wob:   [4][128][64]    Wo
__global__ void k_prep(const float* __restrict__ localW, const float* __restrict__ Wq,
                       const float* __restrict__ Wk, const float* __restrict__ Wv,
                       const float* __restrict__ Wo, unsigned int* __restrict__ lwb,
                       unsigned int* __restrict__ qkvb, unsigned int* __restrict__ wob) {
  int t = blockIdx.x * 256 + threadIdx.x;
  if (t < 40960) {
    int cp = t & 63, k = (t >> 6) & 127, l = t >> 13;
    const float* s = localW + ((size_t)(l * 128 + k) * 128 + 2 * cp);
    lwb[t] = pack_bf(s[0], s[1]);
  }
  int t2 = t - 40960;
  if (t2 >= 0 && t2 < 98304) {
    int l = t2 / 24576, rem = t2 % 24576;
    int m = rem >> 13, k = (rem >> 6) & 127, cp = rem & 63;
    const float* base = (m == 0) ? Wq : ((m == 1) ? Wk : Wv);
    const float* s = base + ((size_t)l * 16384 + k * 128 + 2 * cp);
    qkvb[t2] = pack_bf(s[0], s[1]);
  }
  int t3 = t - 139264;
  if (t3 >= 0 && t3 < 32768) {
    int l = t3 >> 13, k = (t3 >> 6) & 127, cp = t3 & 63;
    const float* s = Wo + ((size_t)l * 16384 + k * 128 + 2 * cp);
    wob[t3] = pack_bf(s[0], s[1]);
  }
}

// ---------------- fold pair_W/pair_b into per-layer 4xH bias weights ----------------
__global__ void k_weff(const float* __restrict__ pair_W, const float* __restrict__ pair_b,
                       const float* __restrict__ Wb, float* __restrict__ weff,
                       float* __restrict__ beff) {
  int t = threadIdx.x;
  if (t >= NIPA_ * 5 * H_) return;  // 160
  int l = t / (5 * H_);
  int rest = t % (5 * H_);
  int c = rest / H_;
  int h = rest % H_;
  const float* row = (c < 4) ? (pair_W + c * D_) : pair_b;
  float acc = 0.f;
  for (int d = 0; d < D_; d++) acc += row[d] * Wb[l * D_ * H_ + d * H_ + h];
  if (c < 4)
    weff[l * 4 * H_ + c * H_ + h] = acc;
  else
    beff[l * H_ + h] = acc;
}

// ---------------- pooling via binary search on sorted res_map (no atomics) ----------------
__global__ void k_pool(const float* __restrict__ coords, const int* __restrict__ atype,
                       const int* __restrict__ rtype, const int* __restrict__ res_map,
                       const float* __restrict__ atom_emb, const float* __restrict__ res_emb,
                       const float* __restrict__ coord_W, const float* __restrict__ coord_b,
                       float* __restrict__ feats0) {
  int row = blockIdx.x;  // b*NR + rr
  int b = row >> 9, rr = row & (NR_ - 1);
  int d = threadIdx.x;
  const int* rm = res_map + b * NA_;
  int lo = 0, hi = NA_;
  while (lo < hi) { int mid = (lo + hi) >> 1; if (rm[mid] < rr) lo = mid + 1; else hi = mid; }
  int start = lo;
  hi = NA_;
  while (lo < hi) { int mid = (lo + hi) >> 1; if (rm[mid] < rr + 1) lo = mid + 1; else hi = mid; }
  int end = lo;
  float w0 = coord_W[d], w1 = coord_W[D_ + d], w2 = coord_W[2 * D_ + d], cb = coord_b[d];
  float s = 0.f;
  for (int a = start; a < end; a++) {
    int ga = b * NA_ + a;
    int at = atype[ga], rt = rtype[ga];
    float c0 = coords[ga * 3 + 0], c1 = coords[ga * 3 + 1], c2 = coords[ga * 3 + 2];
    s += atom_emb[at * D_ + d] + res_emb[rt * D_ + d] + c0 * w0 + c1 * w1 + c2 * w2 + cb;
  }
  float cnt = (float)(end - start);
  feats0[row * D_ + d] = s / (cnt + 1e-8f);
}

// ---------------- fused 5-layer local MLP + layer-0 QKV (4 rows/block, wave-per-row) ----
__launch_bounds__(256) __global__
void k_local_qkv(const float* __restrict__ feats0, const unsigned int* __restrict__ lwb,
                 const float* __restrict__ local_b, const unsigned int* __restrict__ qkvb,
                 float* __restrict__ feats, float* __restrict__ qb,
                 unsigned int* __restrict__ kbU, unsigned int* __restrict__ vbU) {
  __shared__ float xs[4][128];
  int tid = threadIdx.x;
  int r = tid >> 6, cp = tid & 63;
  int row = blockIdx.x * 4 + r;
  float2 x2 = *(const float2*)(feats0 + (size_t)row * D_ + 2 * cp);
  xs[r][2 * cp] = x2.x;
  xs[r][2 * cp + 1] = x2.y;
  for (int l = 0; l < NLOCAL_; l++) {
    const unsigned int* W = lwb + l * 8192;
    float a0 = local_b[l * D_ + 2 * cp], a1 = local_b[l * D_ + 2 * cp + 1];
#pragma unroll 16
    for (int k = 0; k < 128; k++) {
      float x = xs[r][k];
      unsigned int pk = W[k * 64 + cp];
      a0 += x * bf_lo(pk);
      a1 += x * bf_hi(pk);
    }
    float y0 = gelu_tanh(a0) + xs[r][2 * cp];
    float y1 = gelu_tanh(a1) + xs[r][2 * cp + 1];
    // wave-lockstep: all lanes finished reading xs[r] before any write below
    xs[r][2 * cp] = y0;
    xs[r][2 * cp + 1] = y1;
  }
  *(float2*)(feats + (size_t)row * D_ + 2 * cp) = make_float2(xs[r][2 * cp], xs[r][2 * cp + 1]);
#pragma unroll
  for (int m = 0; m < 3; m++) {
    const unsigned int* W = qkvb + m * 8192;  // layer 0
    float a0 = 0.f, a1 = 0.f;
#pragma unroll 16
    for (int k = 0; k < 128; k++) {
      float x = xs[r][k];
      unsigned int pk = W[k * 64 + cp];
      a0 += x * bf_lo(pk);
      a1 += x * bf_hi(pk);
    }
    if (m == 0)
      *(float2*)(qb + (size_t)row * D_ + 2 * cp) = make_float2(a0, a1);
    else if (m == 1)
      kbU[row * 64 + cp] = pack_bf(a0, a1);
    else
      vbU[row * 64 + cp] = pack_bf(a0, a1);
  }
}

// ---------------- fused attention for one (b,h), 16 queries per block ----------------
__launch_bounds__(256) __global__
void k_attn(const float* __restrict__ qb, const unsigned int* __restrict__ kbU,
            const unsigned int* __restrict__ vbU, const float* __restrict__ curT,
            const float* __restrict__ res_mask, const float* __restrict__ weff,
            const float* __restrict__ beff, float* __restrict__ ob, int l) {
  int qt = blockIdx.x;  // 0..31
  int bh = blockIdx.y;  // 0..15
  int b = bh >> 3, h = bh & 7;

  __shared__ unsigned int ks[NR_][9];
  __shared__ unsigned int vs[NR_][9];
  __shared__ float ts[NR_][3];
  __shared__ float ms[NR_];
  __shared__ float ps[4][NR_];

  int tid = threadIdx.x;
  for (int idx = tid; idx < NR_ * 8; idx += 256) {
    int row = idx >> 3, u = idx & 7;
    ks[row][u] = kbU[(b * NR_ + row) * 64 + h * 8 + u];
    vs[row][u] = vbU[(b * NR_ + row) * 64 + h * 8 + u];
  }
  for (int idx = tid; idx < NR_; idx += 256) {
    ts[idx][0] = curT[(b * NR_ + idx) * 3 + 0];
    ts[idx][1] = curT[(b * NR_ + idx) * 3 + 1];
    ts[idx][2] = curT[(b * NR_ + idx) * 3 + 2];
    ms[idx] = res_mask[b * NR_ + idx];
  }
  __syncthreads();

  float c0 = weff[l * 32 + 0 * 8 + h];
  float c1 = weff[l * 32 + 1 * 8 + h];
  float c2 = weff[l * 32 + 2 * 8 + h];
  float c3 = weff[l * 32 + 3 * 8 + h];
  float be = beff[l * 8 + h];

  int w = tid >> 6, lane = tid & 63;

  for (int it = 0; it < 4; it++) {
    int i = qt * 16 + w * 4 + it;
    float qreg[16];
    const float* qrow = qb + ((size_t)(b * NR_ + i)) * D_ + h * DH_;
#pragma unroll
    for (int u = 0; u < 4; u++) {
      float4 q4 = *(const float4*)(qrow + 4 * u);
      qreg[4 * u] = q4.x; qreg[4 * u + 1] = q4.y; qreg[4 * u + 2] = q4.z; qreg[4 * u + 3] = q4.w;
    }
    float tix = ts[i][0], tiy = ts[i][1], tiz = ts[i][2];

    float lsum = 0.f;
#pragma unroll
    for (int jj = 0; jj < 8; jj++) {
      int j = lane + 64 * jj;
      float dot = 0.f;
#pragma unroll
      for (int u = 0; u < 8; u++) {
        unsigned int pk = ks[j][u];
        dot += qreg[2 * u] * bf_lo(pk) + qreg[2 * u + 1] * bf_hi(pk);
      }
      float rx = tix - ts[j][0], ry = tiy - ts[j][1], rz = tiz - ts[j][2];
      float dist = sqrtf(rx * rx + ry * ry + rz * rz);
      float L = dot * 0.25f + c0 * rx + c1 * ry + c2 * rz + c3 * dist + be;
      if (ms[j] <= 0.f) L = -1e9f;
      float p = __expf(L);  // no max-shift: logits bounded, softmax shift-invariant
      ps[w][j] = p;         // wave-private
      lsum += p;
    }
#pragma unroll
    for (int m = 1; m < 64; m <<= 1) lsum += __shfl_xor(lsum, m, 64);

    // PV: lane = (cp2 0..7, jg 0..7); j = t*8+jg; 2 cols per lane
    int cp2 = lane & 7, jg = lane >> 3;
    float a0 = 0.f, a1 = 0.f;
#pragma unroll 8
    for (int t = 0; t < 64; t++) {
      int j = t * 8 + jg;
      float p = ps[w][j];  // broadcast across cp2
      unsigned int pk = vs[j][cp2];
      a0 += p * bf_lo(pk);
      a1 += p * bf_hi(pk);
    }
    a0 += __shfl_xor(a0, 8, 64); a0 += __shfl_xor(a0, 16, 64); a0 += __shfl_xor(a0, 32, 64);
    a1 += __shfl_xor(a1, 8, 64); a1 += __shfl_xor(a1, 16, 64); a1 += __shfl_xor(a1, 32, 64);
    if (jg == 0) {
      float inv = 1.f / lsum;
      *(float2*)(ob + ((size_t)(b * NR_ + i)) * D_ + h * DH_ + 2 * cp2) =
          make_float2(a0 * inv, a1 * inv);
    }
  }
}

// ---------------- oproj(l) + residual + QKV(l+1) (4 rows/block) ----------------
__launch_bounds__(256) __global__
void k_oproj_qkv(const float* __restrict__ ob, const unsigned int* __restrict__ wob,
                 const float* __restrict__ bo, const unsigned int* __restrict__ qkvb,
                 float* __restrict__ feats, float* __restrict__ qb,
                 unsigned int* __restrict__ kbU, unsigned int* __restrict__ vbU, int l, int ln) {
  __shared__ float xs[4][128];
  int tid = threadIdx.x;
  int r = tid >> 6, cp = tid & 63;
  int row = blockIdx.x * 4 + r;
  float2 o2 = *(const float2*)(ob + (size_t)row * D_ + 2 * cp);
  xs[r][2 * cp] = o2.x;
  xs[r][2 * cp + 1] = o2.y;
  const unsigned int* W = wob + l * 8192;
  float a0 = bo[l * D_ + 2 * cp], a1 = bo[l * D_ + 2 * cp + 1];
#pragma unroll 16
  for (int k = 0; k < 128; k++) {
    float x = xs[r][k];
    unsigned int pk = W[k * 64 + cp];
    a0 += x * bf_lo(pk);
    a1 += x * bf_hi(pk);
  }
  float2 f2 = *(const float2*)(feats + (size_t)row * D_ + 2 * cp);
  float f0 = f2.x + a0, f1 = f2.y + a1;
  *(float2*)(feats + (size_t)row * D_ + 2 * cp) = make_float2(f0, f1);
  xs[r][2 * cp] = f0;  // lockstep: safe overwrite
  xs[r][2 * cp + 1] = f1;
#pragma unroll
  for (int m = 0; m < 3; m++) {
    const unsigned int* Wm = qkvb + (ln * 3 + m) * 8192;
    float b0 = 0.f, b1 = 0.f;
#pragma unroll 16
    for (int k = 0; k < 128; k++) {
      float x = xs[r][k];
      unsigned int pk = Wm[k * 64 + cp];
      b0 += x * bf_lo(pk);
      b1 += x * bf_hi(pk);
    }
    if (m == 0)
      *(float2*)(qb + (size_t)row * D_ + 2 * cp) = make_float2(b0, b1);
    else if (m == 1)
      kbU[row * 64 + cp] = pack_bf(b0, b1);
    else
      vbU[row * 64 + cp] = pack_bf(b0, b1);
  }
}

// ---------------- oproj(3) + head + frame update (4 rows/block) ----------------
__launch_bounds__(256) __global__
void k_oproj_head(const float* __restrict__ ob, const unsigned int* __restrict__ wob,
                  const float* __restrict__ bo, const float* __restrict__ feats,
                  const float* __restrict__ head_W, const float* __restrict__ head_b,
                  const float* __restrict__ res_mask, float* __restrict__ curR,
                  float* __restrict__ curT) {
  __shared__ float xs[4][128];
  int tid = threadIdx.x;
  int r = tid >> 6, cp = tid & 63;
  int row = blockIdx.x * 4 + r;
  float2 o2 = *(const float2*)(ob + (size_t)row * D_ + 2 * cp);
  xs[r][2 * cp] = o2.x;
  xs[r][2 * cp + 1] = o2.y;
  const int l = NIPA_ - 1;
  const unsigned int* W = wob + l * 8192;
  float a0 = bo[l * D_ + 2 * cp], a1 = bo[l * D_ + 2 * cp + 1];
#pragma unroll 16
  for (int k = 0; k < 128; k++) {
    float x = xs[r][k];
    unsigned int pk = W[k * 64 + cp];
    a0 += x * bf_lo(pk);
    a1 += x * bf_hi(pk);
  }
  float2 f2 = *(const float2*)(feats + (size_t)row * D_ + 2 * cp);
  float f0 = f2.x + a0, f1 = f2.y + a1;
  float pc[6];
#pragma unroll
  for (int c = 0; c < 6; c++)
    pc[c] = f0 * head_W[(2 * cp) * 6 + c] + f1 * head_W[(2 * cp + 1) * 6 + c];
#pragma unroll
  for (int m = 1; m < 64; m <<= 1)
#pragma unroll
    for (int c = 0; c < 6; c++) pc[c] += __shfl_xor(pc[c], m, 64);
  if ((tid & 63) == 0) {
    float u[6];
#pragma unroll
    for (int c = 0; c < 6; c++) u[c] = pc[c] + head_b[c];
    float vx = u[0], vy = u[1], vz = u[2];
    float inv = rsqrtf(1.f + vx * vx + vy * vy + vz * vz);
    float w = inv, x = vx * inv, y = vy * inv, z = vz * inv;
    float Rd[9];
    Rd[0] = 1.f - 2.f * (y * y + z * z); Rd[1] = 2.f * (x * y - w * z); Rd[2] = 2.f * (x * z + w * y);
    Rd[3] = 2.f * (x * y + w * z); Rd[4] = 1.f - 2.f * (x * x + z * z); Rd[5] = 2.f * (y * z - w * x);
    Rd[6] = 2.f * (x * z - w * y); Rd[7] = 2.f * (y * z + w * x); Rd[8] = 1.f - 2.f * (x * x + y * y);
    float Ro[9];
#pragma unroll
    for (int c = 0; c < 9; c++) Ro[c] = curR[row * 9 + c];
    float Rn[9];
#pragma unroll
    for (int i = 0; i < 3; i++)
#pragma unroll
      for (int kk = 0; kk < 3; kk++)
        Rn[i * 3 + kk] = Rd[i * 3 + 0] * Ro[0 * 3 + kk] + Rd[i * 3 + 1] * Ro[1 * 3 + kk] +
                         Rd[i * 3 + 2] * Ro[2 * 3 + kk];
    float tx = curT[row * 3 + 0], ty = curT[row * 3 + 1], tz = curT[row * 3 + 2];
    float ux = u[3], uy = u[4], uz = u[5];
    float ntx = tx + Rn[0] * ux + Rn[1] * uy + Rn[2] * uz;
    float nty = ty + Rn[3] * ux + Rn[4] * uy + Rn[5] * uz;
    float ntz = tz + Rn[6] * ux + Rn[7] * uy + Rn[8] * uz;
    float m = res_mask[row];
#pragma unroll
    for (int c = 0; c < 9; c++) curR[row * 9 + c] = Rn[c];
    curT[row * 3 + 0] = ntx * m;
    curT[row * 3 + 1] = nty * m;
    curT[row * 3 + 2] = ntz * m;
  }
}

// ---------------- final frame composition + output write ----------------
__global__ void k_final(const float* __restrict__ coords, const int* __restrict__ res_map,
                        const float* __restrict__ rots_bad, const float* __restrict__ trans_bad,
                        const float* __restrict__ curR, const float* __restrict__ curT,
                        float* __restrict__ out) {
  int a = blockIdx.x * blockDim.x + threadIdx.x;
  if (a < B_ * NR_) {
#pragma unroll
    for (int c = 0; c < 9; c++) out[a * 9 + c] = curR[a * 9 + c];
    out[B_ * NR_ * 9 + a * 3 + 0] = curT[a * 3 + 0];
    out[B_ * NR_ * 9 + a * 3 + 1] = curT[a * 3 + 1];
    out[B_ * NR_ * 9 + a * 3 + 2] = curT[a * 3 + 2];
  }
  if (a >= B_ * NA_) return;
  int b = a / NA_;
  int r = b * NR_ + res_map[a];
  float x0 = coords[a * 3 + 0], x1 = coords[a * 3 + 1], x2 = coords[a * 3 + 2];
  float R0[9], Rc[9];
#pragma unroll
  for (int c = 0; c < 9; c++) { R0[c] = rots_bad[r * 9 + c]; Rc[c] = curR[r * 9 + c]; }
  float t0x = trans_bad[r * 3 + 0], t0y = trans_bad[r * 3 + 1], t0z = trans_bad[r * 3 + 2];
  float dx = x0 - t0x, dy = x1 - t0y, dz = x2 - t0z;
  float lx = R0[0] * dx + R0[3] * dy + R0[6] * dz;
  float ly = R0[1] * dx + R0[4] * dy + R0[7] * dz;
  float lz = R0[2] * dx + R0[5] * dy + R0[8] * dz;
  float tcx = curT[r * 3 + 0], tcy = curT[r * 3 + 1], tcz = curT[r * 3 + 2];
  float fx = Rc[0] * lx + Rc[3] * ly + Rc[6] * lz + tcx;
  float fy = Rc[1] * lx + Rc[4] * ly + Rc[7] * lz + tcy;
  float fz = Rc[2] * lx + Rc[5] * ly + Rc[8] * lz + tcz;
  int off = B_ * NR_ * 12;
  out[off + a * 3 + 0] = fx;
  out[off + a * 3 + 1] = fy;
  out[off + a * 3 + 2] = fz;
}

extern "C" void kernel_launch(void* const* d_in, const int* in_sizes, int n_in,
                              void* d_out, int out_size, void* d_ws, size_t ws_size,
                              hipStream_t stream) {
  const float* coords    = (const float*)d_in[0];
  const int*   atype     = (const int*)d_in[1];
  const int*   rtype     = (const int*)d_in[2];
  const float* res_mask  = (const float*)d_in[4];
  const int*   res_map   = (const int*)d_in[5];
  const float* rots_bad  = (const float*)d_in[6];
  const float* trans_bad = (const float*)d_in[7];
  const float* atom_emb  = (const float*)d_in[8];
  const float* res_emb   = (const float*)d_in[9];
  const float* coord_W   = (const float*)d_in[10];
  const float* coord_b   = (const float*)d_in[11];
  const float* local_W   = (const float*)d_in[12];
  const float* local_b   = (const float*)d_in[13];
  const float* pair_W    = (const float*)d_in[14];
  const float* pair_b    = (const float*)d_in[15];
  const float* Wq        = (const float*)d_in[16];
  const float* Wk        = (const float*)d_in[17];
  const float* Wv        = (const float*)d_in[18];
  const float* Wb        = (const float*)d_in[19];
  const float* Wo        = (const float*)d_in[20];
  const float* bo        = (const float*)d_in[21];
  const float* head_W    = (const float*)d_in[22];
  const float* head_b    = (const float*)d_in[23];

  float* ws = (float*)d_ws;
  float* feats0 = ws;                       // 131072
  float* feats  = feats0 + 131072;          // 131072
  float* qb     = feats + 131072;           // 131072
  float* ob     = qb + 131072;              // 131072
  float* weff   = ob + 131072;              // 128
  float* beff   = weff + 128;               // 32
  float* curR   = beff + 32;                // 9216
  float* curT   = curR + 9216;              // 3072
  unsigned int* kbU  = (unsigned int*)(curT + 3072);  // 65536
  unsigned int* vbU  = kbU + 65536;                   // 65536
  unsigned int* lwb  = vbU + 65536;                   // 40960
  unsigned int* qkvb = lwb + 40960;                   // 98304
  unsigned int* wob  = qkvb + 98304;                  // 32768

  hipMemcpyAsync(curR, rots_bad, 9216 * sizeof(float), hipMemcpyDeviceToDevice, stream);
  hipMemcpyAsync(curT, trans_bad, 3072 * sizeof(float), hipMemcpyDeviceToDevice, stream);

  k_prep<<<672, 256, 0, stream>>>(local_W, Wq, Wk, Wv, Wo, lwb, qkvb, wob);
  k_weff<<<1, 192, 0, stream>>>(pair_W, pair_b, Wb, weff, beff);
  k_pool<<<B_ * NR_, D_, 0, stream>>>(coords, atype, rtype, res_map, atom_emb, res_emb,
                                      coord_W, coord_b, feats0);

  for (int iter = 0; iter < NITER_; iter++) {
    k_local_qkv<<<B_ * NR_ / 4, 256, 0, stream>>>(feats0, lwb, local_b, qkvb, feats, qb, kbU,
                                                  vbU);
    for (int l = 0; l < NIPA_; l++) {
      k_attn<<<dim3(NR_ / 16, B_ * H_), 256, 0, stream>>>(qb, kbU, vbU, curT, res_mask, weff,
                                                          beff, ob, l);
      if (l < NIPA_ - 1) {
        k_oproj_qkv<<<B_ * NR_ / 4, 256, 0, stream>>>(ob, wob, bo, qkvb, feats, qb, kbU, vbU,
                                                      l, l + 1);
      } else {
        k_oproj_head<<<B_ * NR_ / 4, 256, 0, stream>>>(ob, wob, bo, feats, head_W, head_b,
                                                       res_mask, curR, curT);
      }
    }
  }
  k_final<<<(B_ * NA_ + 255) / 256, 256, 0, stream>>>(coords, res_map, rots_bad, trans_bad,
                                                      curR, curT, (float*)d_out);
}